// Round 4
// baseline (557.025 us; speedup 1.0000x reference)
//
#include <hip/hip_runtime.h>
#include <hip/hip_bf16.h>

#define T_TOK 2048
#define H_DIM 1024
#define E_EXP 32
#define F_DIM 512
#define FS_DIM 1024
#define K_TOP 8
#define NGRP 8
#define TGRP 4
#define GSZ (E_EXP / NGRP)
#define RSCALE 2.5f
#define CAP 2048

typedef short  short8 __attribute__((ext_vector_type(8)));
typedef __bf16 bf16x4 __attribute__((ext_vector_type(4)));
typedef float  f32x4  __attribute__((ext_vector_type(4)));

// ---------------- fp32 -> bf16 conversion ----------------
__global__ void cvt_f32_bf16(const float* __restrict__ src, __bf16* __restrict__ dst, int n4) {
  int i = blockIdx.x * blockDim.x + threadIdx.x;
  const int stride = gridDim.x * blockDim.x;
  for (; i < n4; i += stride) {
    const float4 v = reinterpret_cast<const float4*>(src)[i];
    bf16x4 o;
    o[0] = (__bf16)v.x; o[1] = (__bf16)v.y; o[2] = (__bf16)v.z; o[3] = (__bf16)v.w;
    reinterpret_cast<bf16x4*>(dst)[i] = o;
  }
}

// ---------------- routing (fp32, exact reference semantics) ----------------
__global__ __launch_bounds__(64) void route_kernel(
    const float* __restrict__ x, const float* __restrict__ gw,
    const float* __restrict__ bias, int* __restrict__ tk_idx, float* __restrict__ tk_w) {
  const int t = blockIdx.x;
  const int lane = threadIdx.x;
  float xr[16];
#pragma unroll
  for (int i = 0; i < 16; i++) xr[i] = x[t * H_DIM + i * 64 + lane];
  float sc[E_EXP];
#pragma unroll
  for (int e = 0; e < E_EXP; e++) {
    const float* w = gw + e * H_DIM;
    float s = 0.f;
#pragma unroll
    for (int i = 0; i < 16; i++) s += xr[i] * w[i * 64 + lane];
#pragma unroll
    for (int off = 32; off > 0; off >>= 1) s += __shfl_xor(s, off);
    sc[e] = 1.f / (1.f + expf(-s));
  }
  if (lane == 0) {
    float b[E_EXP];
    for (int e = 0; e < E_EXP; e++) b[e] = sc[e] + bias[e];
    float gs[NGRP];
    for (int g = 0; g < NGRP; g++) {
      float m1 = -1e30f, m2 = -1e30f;
      for (int j = 0; j < GSZ; j++) {
        float v = b[g * GSZ + j];
        if (v > m1) { m2 = m1; m1 = v; } else if (v > m2) { m2 = v; }
      }
      gs[g] = m1 + m2;
    }
    unsigned gmask = 0;
    for (int it = 0; it < TGRP; it++) {
      float best = -1e30f; int bi = 0;
      for (int g = 0; g < NGRP; g++)
        if (!((gmask >> g) & 1) && gs[g] > best) { best = gs[g]; bi = g; }
      gmask |= 1u << bi;
    }
    unsigned emask = 0; float wsum = 0.f;
    int idx8[K_TOP];
    for (int it = 0; it < K_TOP; it++) {
      float best = -1e30f; int bi = 0;
      for (int e = 0; e < E_EXP; e++) {
        if (!((gmask >> (e / GSZ)) & 1)) continue;
        if ((emask >> e) & 1) continue;
        if (b[e] > best) { best = b[e]; bi = e; }
      }
      emask |= 1u << bi;
      idx8[it] = bi;
      wsum += sc[bi];
    }
    const float inv = 1.f / (wsum + 1e-20f);
    for (int k = 0; k < K_TOP; k++) {
      tk_idx[t * K_TOP + k] = idx8[k];
      tk_w[t * K_TOP + k] = sc[idx8[k]] * inv;
    }
  }
}

// ---------------- scatter: build per-expert token lists ----------------
__global__ void scatter_kernel(const int* __restrict__ tk_idx, int* __restrict__ counts,
                               int* __restrict__ recs) {
  const int i = blockIdx.x * blockDim.x + threadIdx.x;
  if (i >= T_TOK * K_TOP) return;
  const int e = tk_idx[i];
  const int pos = atomicAdd(&counts[e], 1);
  recs[e * CAP + pos] = i;  // i == t*8 + k
}

__global__ void offsets_kernel(const int* __restrict__ counts, int* __restrict__ offs) {
  if (threadIdx.x == 0) {
    int a = 0;
    for (int e = 0; e < E_EXP; e++) { offs[e] = a; a += counts[e]; }
  }
}

#define BK 64

__device__ __forceinline__ void gload_lds16(const void* g, void* l) {
  __builtin_amdgcn_global_load_lds(
      (__attribute__((address_space(1))) const void*)g,
      (__attribute__((address_space(3))) void*)l, 16, 0, 0);
}

// ================= 256x256 double-buffered grouped GEMM (GU / DOWN) =================
// waves: 8 as 2(M) x 4(N); per-wave output 128x64; minimum-2-phase prefetch schedule.
template <int MODE>  // 0 = GU (silu(gate)*up -> h_buf bf16), 1 = DOWN (-> y_slot f32, weighted)
__global__ __launch_bounds__(512, 2) void gemm256_kernel(
    const __bf16* __restrict__ Abase, const __bf16* __restrict__ Bbase,
    void* __restrict__ Out,
    const int* __restrict__ recs, const int* __restrict__ counts,
    const int* __restrict__ offs, const float* __restrict__ tk_w) {

  constexpr int K = (MODE == 0) ? H_DIM : F_DIM;
  const int e = blockIdx.z;
  const int m0 = blockIdx.y * 256;
  const int count = counts[e];
  const int off_e = offs[e];
  if (m0 >= count) return;
  const int bx = blockIdx.x;
  const int tid = threadIdx.x, wid = tid >> 6, lane = tid & 63;
  const int wr = wid >> 2, wc = wid & 3;
  const int lr = lane & 15, lh = lane >> 4;

  __shared__ __align__(16) __bf16 As[2][256 * BK];   // 2 x 32 KB
  __shared__ __align__(16) __bf16 Bs[2][256 * BK];   // 2 x 32 KB

  const int colk = (lane & 7) * 8;
  const __bf16* aptr[4];
  const __bf16* bptr[4];
#pragma unroll
  for (int i = 0; i < 4; i++) {
    const int row = wid * 32 + i * 8 + (lane >> 3);   // tile row staged by this lane
    int r = m0 + row; if (r > count - 1) r = count - 1;
    if (MODE == 0) {
      const int rec = recs[e * CAP + r];
      aptr[i] = Abase + (size_t)(rec >> 3) * H_DIM + colk;      // gather token row of xb
    } else {
      aptr[i] = Abase + (size_t)(off_e + r) * F_DIM + colk;     // dense h slab
    }
    int brow;
    if (MODE == 0) {
      // tile cols per 64-block: [0,32) gate, [32,64) up, f = bx*128 + wcb*32 + (sub&31)
      const int sub = row & 63, wcb = row >> 6;
      const int f = bx * 128 + wcb * 32 + (sub & 31);
      brow = (sub < 32) ? f : (F_DIM + f);
      bptr[i] = Bbase + (size_t)e * 2 * F_DIM * H_DIM + (size_t)brow * H_DIM + colk;
    } else {
      brow = bx * 256 + row;
      bptr[i] = Bbase + (size_t)e * H_DIM * F_DIM + (size_t)brow * F_DIM + colk;
    }
  }

  f32x4 acc[8][4];
#pragma unroll
  for (int a = 0; a < 8; a++)
#pragma unroll
    for (int b = 0; b < 4; b++) acc[a][b] = f32x4{0.f, 0.f, 0.f, 0.f};

  constexpr int NT = K / BK;

  // prologue: stage tile 0
#pragma unroll
  for (int i = 0; i < 4; i++) {
    gload_lds16(aptr[i], (char*)&As[0][0] + (wid * 32 + i * 8) * 128);
    gload_lds16(bptr[i], (char*)&Bs[0][0] + (wid * 32 + i * 8) * 128);
  }
  __syncthreads();

  int cur = 0;
  for (int t = 0; t < NT; ++t) {
    if (t + 1 < NT) {
      const int k0 = (t + 1) * BK;
#pragma unroll
      for (int i = 0; i < 4; i++) {
        gload_lds16(aptr[i] + k0, (char*)&As[cur ^ 1][0] + (wid * 32 + i * 8) * 128);
        gload_lds16(bptr[i] + k0, (char*)&Bs[cur ^ 1][0] + (wid * 32 + i * 8) * 128);
      }
    }
#pragma unroll
    for (int kk = 0; kk < 2; kk++) {
      short8 af[8], bfr[4];
#pragma unroll
      for (int fm = 0; fm < 8; fm++)
        af[fm] = *reinterpret_cast<const short8*>(&As[cur][(wr * 128 + fm * 16 + lr) * BK + kk * 32 + lh * 8]);
#pragma unroll
      for (int fn = 0; fn < 4; fn++)
        bfr[fn] = *reinterpret_cast<const short8*>(&Bs[cur][(wc * 64 + fn * 16 + lr) * BK + kk * 32 + lh * 8]);
#pragma unroll
      for (int fn = 0; fn < 4; fn++)
#pragma unroll
        for (int fm = 0; fm < 8; fm++)
          acc[fm][fn] = __builtin_amdgcn_mfma_f32_16x16x32_bf16(af[fm], bfr[fn], acc[fm][fn], 0, 0, 0);
    }
    __syncthreads();   // implicit vmcnt(0) drain makes next buffer ready; protects cur buffer reuse
    cur ^= 1;
  }

  if (MODE == 0) {
    __bf16* h_out = (__bf16*)Out;
#pragma unroll
    for (int fm = 0; fm < 8; fm++)
#pragma unroll
      for (int j = 0; j < 4; j++) {
        const int row = wr * 128 + fm * 16 + lh * 4 + j;
        if (m0 + row < count) {
#pragma unroll
          for (int fn = 0; fn < 2; fn++) {
            const float g = acc[fm][fn][j], u = acc[fm][fn + 2][j];
            const float hv = g / (1.f + expf(-g)) * u;
            const int f = bx * 128 + wc * 32 + fn * 16 + lr;
            h_out[(size_t)(off_e + m0 + row) * F_DIM + f] = (__bf16)hv;
          }
        }
      }
  } else {
    float* y = (float*)Out;
#pragma unroll
    for (int fm = 0; fm < 8; fm++)
#pragma unroll
      for (int j = 0; j < 4; j++) {
        const int row = wr * 128 + fm * 16 + lh * 4 + j;
        if (m0 + row < count) {
          const int rec = recs[e * CAP + m0 + row];   // == t*8+k, the y_slot row
          const float w = tk_w[rec];
          const size_t base = (size_t)rec * H_DIM + bx * 256;
#pragma unroll
          for (int fn = 0; fn < 4; fn++)
            y[base + wc * 64 + fn * 16 + lr] = acc[fm][fn][j] * w;
        }
      }
  }
}

// ================= 128x128 dense GEMM for shared expert (round-2 structure) =================
#define BM 128
#define BN 128

constexpr int MODE_SGU = 2, MODE_SDOWN = 3;

template <int MODE>
__global__ __launch_bounds__(256) void gemm_kernel(
    const __bf16* __restrict__ Abase, const __bf16* __restrict__ Bbase,
    void* __restrict__ Out) {

  constexpr int K = (MODE == MODE_SDOWN) ? FS_DIM : H_DIM;
  const int m0 = blockIdx.y * BM;
  const int tid = threadIdx.x, wid = tid >> 6, lane = tid & 63;

  __shared__ __align__(16) __bf16 As[BM * BK];
  __shared__ __align__(16) __bf16 Bs[BN * BK];

  const int colk = (lane & 7) * 8;
  const __bf16* aptr[4];
  const __bf16* bptr[4];
#pragma unroll
  for (int i = 0; i < 4; i++) {
    const int row = wid * 32 + i * 8 + (lane >> 3);
    aptr[i] = Abase + (size_t)(m0 + row) * K + colk;
    int brow;
    if (MODE == MODE_SGU) brow = (row < 64) ? (blockIdx.x * 64 + row) : (FS_DIM + blockIdx.x * 64 + row - 64);
    else                  brow = blockIdx.x * BN + row;
    bptr[i] = Bbase + (size_t)brow * K + colk;
  }

  f32x4 acc[2][8];
#pragma unroll
  for (int a = 0; a < 2; a++)
#pragma unroll
    for (int b = 0; b < 8; b++) acc[a][b] = f32x4{0.f, 0.f, 0.f, 0.f};

  const int lr = lane & 15, lh = lane >> 4;

  for (int k0 = 0; k0 < K; k0 += BK) {
#pragma unroll
    for (int i = 0; i < 4; i++)
      gload_lds16(aptr[i] + k0, (char*)As + (wid * 4 + i) * 1024);
#pragma unroll
    for (int i = 0; i < 4; i++)
      gload_lds16(bptr[i] + k0, (char*)Bs + (wid * 4 + i) * 1024);
    __syncthreads();
#pragma unroll
    for (int kk = 0; kk < 2; kk++) {
      short8 af[2], bfr[8];
#pragma unroll
      for (int fm = 0; fm < 2; fm++)
        af[fm] = *reinterpret_cast<const short8*>(&As[(wid * 32 + fm * 16 + lr) * BK + kk * 32 + lh * 8]);
#pragma unroll
      for (int fn = 0; fn < 8; fn++)
        bfr[fn] = *reinterpret_cast<const short8*>(&Bs[(fn * 16 + lr) * BK + kk * 32 + lh * 8]);
#pragma unroll
      for (int fn = 0; fn < 8; fn++)
#pragma unroll
        for (int fm = 0; fm < 2; fm++)
          acc[fm][fn] = __builtin_amdgcn_mfma_f32_16x16x32_bf16(af[fm], bfr[fn], acc[fm][fn], 0, 0, 0);
    }
    __syncthreads();
  }

  if (MODE == MODE_SGU) {
    __bf16* h_out = (__bf16*)Out;
#pragma unroll
    for (int fm = 0; fm < 2; fm++)
#pragma unroll
      for (int j = 0; j < 4; j++) {
        const int row = wid * 32 + fm * 16 + lh * 4 + j;
#pragma unroll
        for (int fn = 0; fn < 4; fn++) {
          const float g = acc[fm][fn][j], u = acc[fm][fn + 4][j];
          const float hv = g / (1.f + expf(-g)) * u;
          const int f = blockIdx.x * 64 + fn * 16 + lr;
          h_out[(size_t)(m0 + row) * FS_DIM + f] = (__bf16)hv;
        }
      }
  } else {
    float* o = (float*)Out;
#pragma unroll
    for (int fm = 0; fm < 2; fm++)
#pragma unroll
      for (int j = 0; j < 4; j++) {
        const int row = wid * 32 + fm * 16 + lh * 4 + j;
#pragma unroll
        for (int fn = 0; fn < 8; fn++)
          o[(size_t)(m0 + row) * H_DIM + blockIdx.x * BN + fn * 16 + lr] = acc[fm][fn][j];
      }
  }
}

// ---------------- combine: out = shared + SCALE * sum_k y_slot[t,k] ----------------
__global__ void combine_kernel(const float* __restrict__ y_slot, float* __restrict__ out) {
  const int gid = blockIdx.x * blockDim.x + threadIdx.x;
  const int t = gid >> 8;
  const int c0 = (gid & 255) * 4;
  float4 s = {0.f, 0.f, 0.f, 0.f};
#pragma unroll
  for (int k = 0; k < K_TOP; k++) {
    const float4 v = *reinterpret_cast<const float4*>(&y_slot[((size_t)t * K_TOP + k) * H_DIM + c0]);
    s.x += v.x; s.y += v.y; s.z += v.z; s.w += v.w;
  }
  float4 o = *reinterpret_cast<float4*>(&out[(size_t)t * H_DIM + c0]);
  o.x += RSCALE * s.x; o.y += RSCALE * s.y; o.z += RSCALE * s.z; o.w += RSCALE * s.w;
  *reinterpret_cast<float4*>(&out[(size_t)t * H_DIM + c0]) = o;
}

// ---------------- launch ----------------
extern "C" void kernel_launch(void* const* d_in, const int* in_sizes, int n_in,
                              void* d_out, int out_size, void* d_ws, size_t ws_size,
                              hipStream_t stream) {
  const float* x    = (const float*)d_in[0];
  const float* gw   = (const float*)d_in[1];
  const float* bias = (const float*)d_in[2];
  const float* wgu  = (const float*)d_in[3];
  const float* wd   = (const float*)d_in[4];
  const float* sgu  = (const float*)d_in[5];
  const float* sd   = (const float*)d_in[6];

  char* ws = (char*)d_ws;
  size_t o = 0;
  auto alloc = [&](size_t bytes) {
    char* p = ws + o;
    o += (bytes + 255) & ~(size_t)255;
    return (void*)p;
  };
  __bf16* xb     = (__bf16*)alloc((size_t)T_TOK * H_DIM * 2);
  __bf16* wgub   = (__bf16*)alloc((size_t)E_EXP * 2 * F_DIM * H_DIM * 2);
  __bf16* wdb    = (__bf16*)alloc((size_t)E_EXP * H_DIM * F_DIM * 2);
  __bf16* sgub   = (__bf16*)alloc((size_t)2 * FS_DIM * H_DIM * 2);
  __bf16* sdb    = (__bf16*)alloc((size_t)H_DIM * FS_DIM * 2);
  __bf16* h_buf  = (__bf16*)alloc((size_t)T_TOK * K_TOP * F_DIM * 2);
  float*  y_slot = (float*) alloc((size_t)T_TOK * K_TOP * H_DIM * 4);
  __bf16* hs     = (__bf16*)alloc((size_t)T_TOK * FS_DIM * 2);
  int*   tk_idx  = (int*)  alloc((size_t)T_TOK * K_TOP * 4);
  float* tk_w    = (float*)alloc((size_t)T_TOK * K_TOP * 4);
  int*   counts  = (int*)  alloc((size_t)E_EXP * 4);
  int*   offs    = (int*)  alloc((size_t)E_EXP * 4);
  int*   recs    = (int*)  alloc((size_t)E_EXP * CAP * 4);
  if (o > ws_size) return;

  // 1. conversions
  cvt_f32_bf16<<<2048, 256, 0, stream>>>(x,   xb,   T_TOK * H_DIM / 4);
  cvt_f32_bf16<<<2048, 256, 0, stream>>>(wgu, wgub, E_EXP * 2 * F_DIM * H_DIM / 4);
  cvt_f32_bf16<<<2048, 256, 0, stream>>>(wd,  wdb,  E_EXP * H_DIM * F_DIM / 4);
  cvt_f32_bf16<<<2048, 256, 0, stream>>>(sgu, sgub, 2 * FS_DIM * H_DIM / 4);
  cvt_f32_bf16<<<1024, 256, 0, stream>>>(sd,  sdb,  H_DIM * FS_DIM / 4);

  // 2. routing
  route_kernel<<<T_TOK, 64, 0, stream>>>(x, gw, bias, tk_idx, tk_w);

  // 3. scatter
  hipMemsetAsync(counts, 0, E_EXP * 4, stream);
  scatter_kernel<<<(T_TOK * K_TOP + 255) / 256, 256, 0, stream>>>(tk_idx, counts, recs);
  offsets_kernel<<<1, 64, 0, stream>>>(counts, offs);

  // 4. grouped GEMMs (256^2 double-buffered) + shared (128^2)
  gemm256_kernel<0><<<dim3(2 * F_DIM / 256, CAP / 256, E_EXP), 512, 0, stream>>>(xb, wgub, h_buf, recs, counts, offs, tk_w);
  gemm256_kernel<1><<<dim3(H_DIM / 256, CAP / 256, E_EXP), 512, 0, stream>>>(h_buf, wdb, y_slot, recs, counts, offs, tk_w);
  gemm_kernel<MODE_SGU>  <<<dim3(FS_DIM / 64, T_TOK / BM), 256, 0, stream>>>(xb, sgub, hs);
  gemm_kernel<MODE_SDOWN><<<dim3(H_DIM / BN, T_TOK / BM), 256, 0, stream>>>(hs, sdb, d_out);

  // 5. combine
  combine_kernel<<<T_TOK * H_DIM / 4 / 256, 256, 0, stream>>>(y_slot, (float*)d_out);
}

// Round 5
// 363.975 us; speedup vs baseline: 1.5304x; 1.5304x over previous
//
#include <hip/hip_runtime.h>
#include <hip/hip_bf16.h>

#define T_TOK 2048
#define H_DIM 1024
#define E_EXP 32
#define F_DIM 512
#define FS_DIM 1024
#define K_TOP 8
#define NGRP 8
#define TGRP 4
#define GSZ (E_EXP / NGRP)
#define RSCALE 2.5f
#define CAP 2048

typedef short  short8 __attribute__((ext_vector_type(8)));
typedef __bf16 bf16x4 __attribute__((ext_vector_type(4)));
typedef float  f32x4  __attribute__((ext_vector_type(4)));

// ---------------- fused fp32 -> bf16 conversion for all 4 weight tensors ----------------
__global__ void cvt_all(const float* __restrict__ s0, __bf16* __restrict__ d0, int n0,
                        const float* __restrict__ s1, __bf16* __restrict__ d1, int n1,
                        const float* __restrict__ s2, __bf16* __restrict__ d2, int n2,
                        const float* __restrict__ s3, __bf16* __restrict__ d3, int n3) {
  const int ntot = n0 + n1 + n2 + n3;
  int gid = blockIdx.x * blockDim.x + threadIdx.x;
  const int stride = gridDim.x * blockDim.x;
  for (; gid < ntot; gid += stride) {
    int i = gid;
    const float* src; __bf16* dst;
    if (i < n0) { src = s0; dst = d0; }
    else { i -= n0;
      if (i < n1) { src = s1; dst = d1; }
      else { i -= n1;
        if (i < n2) { src = s2; dst = d2; }
        else { i -= n2; src = s3; dst = d3; }
      }
    }
    const float4 v = reinterpret_cast<const float4*>(src)[i];
    bf16x4 o;
    o[0] = (__bf16)v.x; o[1] = (__bf16)v.y; o[2] = (__bf16)v.z; o[3] = (__bf16)v.w;
    reinterpret_cast<bf16x4*>(dst)[i] = o;
  }
}

// ---------------- routing + scatter + x->bf16 (fp32 selection, exact reference semantics) ----------------
__global__ __launch_bounds__(64) void route_kernel(
    const float* __restrict__ x, const float* __restrict__ gw,
    const float* __restrict__ bias, float* __restrict__ tk_w,
    int* __restrict__ counts, int* __restrict__ recs, __bf16* __restrict__ xb) {
  const int t = blockIdx.x;
  const int lane = threadIdx.x;
  float xr[16];
#pragma unroll
  for (int i = 0; i < 16; i++) xr[i] = x[t * H_DIM + i * 64 + lane];
  // fold x->bf16 conversion in here (row already resident)
#pragma unroll
  for (int i = 0; i < 16; i++) xb[t * H_DIM + i * 64 + lane] = (__bf16)xr[i];
  float sc[E_EXP];
#pragma unroll
  for (int e = 0; e < E_EXP; e++) {
    const float* w = gw + e * H_DIM;
    float s = 0.f;
#pragma unroll
    for (int i = 0; i < 16; i++) s += xr[i] * w[i * 64 + lane];
#pragma unroll
    for (int off = 32; off > 0; off >>= 1) s += __shfl_xor(s, off);
    sc[e] = 1.f / (1.f + expf(-s));
  }
  if (lane == 0) {
    float b[E_EXP];
    for (int e = 0; e < E_EXP; e++) b[e] = sc[e] + bias[e];
    float gs[NGRP];
    for (int g = 0; g < NGRP; g++) {
      float m1 = -1e30f, m2 = -1e30f;
      for (int j = 0; j < GSZ; j++) {
        float v = b[g * GSZ + j];
        if (v > m1) { m2 = m1; m1 = v; } else if (v > m2) { m2 = v; }
      }
      gs[g] = m1 + m2;
    }
    unsigned gmask = 0;
    for (int it = 0; it < TGRP; it++) {
      float best = -1e30f; int bi = 0;
      for (int g = 0; g < NGRP; g++)
        if (!((gmask >> g) & 1) && gs[g] > best) { best = gs[g]; bi = g; }
      gmask |= 1u << bi;
    }
    unsigned emask = 0; float wsum = 0.f;
    int idx8[K_TOP];
    for (int it = 0; it < K_TOP; it++) {
      float best = -1e30f; int bi = 0;
      for (int e = 0; e < E_EXP; e++) {
        if (!((gmask >> (e / GSZ)) & 1)) continue;
        if ((emask >> e) & 1) continue;
        if (b[e] > best) { best = b[e]; bi = e; }
      }
      emask |= 1u << bi;
      idx8[it] = bi;
      wsum += sc[bi];
    }
    const float inv = 1.f / (wsum + 1e-20f);
    for (int k = 0; k < K_TOP; k++) {
      const int e = idx8[k];
      tk_w[t * K_TOP + k] = sc[e] * inv;
      const int pos = atomicAdd(&counts[e], 1);
      recs[e * CAP + pos] = t * K_TOP + k;
    }
  }
}

// ---------------- fused grouped+shared GEMM (round-2 m97 structure, 128x128, BK=64) ----------------
#define BM 128
#define BN 128
#define BK 64

__device__ __forceinline__ void gload_lds16(const void* g, void* l) {
  __builtin_amdgcn_global_load_lds(
      (__attribute__((address_space(1))) const void*)g,
      (__attribute__((address_space(3))) void*)l, 16, 0, 0);
}

// PHASE 0: z<32 -> GU expert z (A=xb gather, B=wgub, out=h_buf bf16 silu*up)
//          z in {32,33} -> shared GU slice s=z-32 (A=xb dense, B=sgub, out=hs)
// PHASE 1: z<32 -> DOWN expert z (A=h_buf slab, B=wdb, out=y_slot fp32 * tk_w)
//          z==32 -> shared DOWN (A=hs dense, B=sdb, out=d_out fp32)
template <int PHASE>
__global__ __launch_bounds__(256) void gemm_fused(
    const __bf16* __restrict__ Ar, const __bf16* __restrict__ As_,
    const __bf16* __restrict__ Br, const __bf16* __restrict__ Bs_,
    void* __restrict__ OutR, void* __restrict__ OutS,
    const int* __restrict__ recs, const int* __restrict__ counts,
    const float* __restrict__ tk_w) {

  const int z = blockIdx.z;
  const bool routed = (z < E_EXP);
  const int e = z;
  const int m0 = blockIdx.y * BM;
  const int bx = blockIdx.x;

  int count = T_TOK, off_e = 0;
  if (routed) {
    count = counts[e];
    for (int i = 0; i < E_EXP; i++) off_e += (i < e) ? counts[i] : 0;
    if (m0 >= count) return;
  }
  const int K = (PHASE == 0) ? H_DIM : (routed ? F_DIM : FS_DIM);

  const int tid = threadIdx.x, wid = tid >> 6, lane = tid & 63;

  __shared__ __align__(16) __bf16 Atile[BM * BK];
  __shared__ __align__(16) __bf16 Btile[BN * BK];

  const int colk = (lane & 7) * 8;
  const __bf16* aptr[4];
  const __bf16* bptr[4];
#pragma unroll
  for (int i = 0; i < 4; i++) {
    const int row = wid * 32 + i * 8 + (lane >> 3);
    int r = m0 + row; if (r > count - 1) r = count - 1;
    // ---- A source ----
    if (PHASE == 0) {
      if (routed) {
        const int rec = recs[e * CAP + r];
        aptr[i] = Ar + (size_t)(rec >> 3) * H_DIM + colk;     // gather token row of xb
      } else {
        aptr[i] = As_ + (size_t)r * H_DIM + colk;             // dense xb
      }
    } else {
      if (routed) aptr[i] = Ar + (size_t)(off_e + r) * F_DIM + colk;   // h slab
      else        aptr[i] = As_ + (size_t)r * FS_DIM + colk;           // hs dense
    }
    // ---- B source ----
    if (PHASE == 0) {
      if (routed) {
        const int brow = (row < 64) ? (bx * 64 + row) : (F_DIM + bx * 64 + row - 64);
        bptr[i] = Br + (size_t)e * 2 * F_DIM * H_DIM + (size_t)brow * H_DIM + colk;
      } else {
        const int s = z - E_EXP;
        const int fglob = s * 512 + bx * 64 + (row & 63);
        const int brow = (row < 64) ? fglob : (FS_DIM + fglob);
        bptr[i] = Bs_ + (size_t)brow * H_DIM + colk;
      }
    } else {
      if (routed) {
        const int brow = bx * BN + row;
        bptr[i] = Br + (size_t)e * H_DIM * F_DIM + (size_t)brow * F_DIM + colk;
      } else {
        const int brow = bx * BN + row;
        bptr[i] = Bs_ + (size_t)brow * FS_DIM + colk;
      }
    }
  }

  f32x4 acc[2][8];
#pragma unroll
  for (int a = 0; a < 2; a++)
#pragma unroll
    for (int b = 0; b < 8; b++) acc[a][b] = f32x4{0.f, 0.f, 0.f, 0.f};

  const int lr = lane & 15, lh = lane >> 4;

  for (int k0 = 0; k0 < K; k0 += BK) {
#pragma unroll
    for (int i = 0; i < 4; i++)
      gload_lds16(aptr[i] + k0, (char*)Atile + (wid * 4 + i) * 1024);
#pragma unroll
    for (int i = 0; i < 4; i++)
      gload_lds16(bptr[i] + k0, (char*)Btile + (wid * 4 + i) * 1024);
    __syncthreads();
#pragma unroll
    for (int kk = 0; kk < 2; kk++) {
      short8 af[2], bfr[8];
#pragma unroll
      for (int fm = 0; fm < 2; fm++)
        af[fm] = *reinterpret_cast<const short8*>(&Atile[(wid * 32 + fm * 16 + lr) * BK + kk * 32 + lh * 8]);
#pragma unroll
      for (int fn = 0; fn < 8; fn++)
        bfr[fn] = *reinterpret_cast<const short8*>(&Btile[(fn * 16 + lr) * BK + kk * 32 + lh * 8]);
#pragma unroll
      for (int fn = 0; fn < 8; fn++)
#pragma unroll
        for (int fm = 0; fm < 2; fm++)
          acc[fm][fn] = __builtin_amdgcn_mfma_f32_16x16x32_bf16(af[fm], bfr[fn], acc[fm][fn], 0, 0, 0);
    }
    __syncthreads();
  }

  // ---------------- epilogues ----------------
  if (PHASE == 0) {
    // silu(gate) * up -> bf16
#pragma unroll
    for (int fm = 0; fm < 2; fm++)
#pragma unroll
      for (int j = 0; j < 4; j++) {
        const int row = wid * 32 + fm * 16 + lh * 4 + j;
        if (m0 + row < count) {
#pragma unroll
          for (int fn = 0; fn < 4; fn++) {
            const float g = acc[fm][fn][j], u = acc[fm][fn + 4][j];
            const float hv = g / (1.f + expf(-g)) * u;
            if (routed) {
              const int f = bx * 64 + fn * 16 + lr;
              ((__bf16*)OutR)[(size_t)(off_e + m0 + row) * F_DIM + f] = (__bf16)hv;
            } else {
              const int s = z - E_EXP;
              const int f = s * 512 + bx * 64 + fn * 16 + lr;
              ((__bf16*)OutS)[(size_t)(m0 + row) * FS_DIM + f] = (__bf16)hv;
            }
          }
        }
      }
  } else {
#pragma unroll
    for (int fm = 0; fm < 2; fm++)
#pragma unroll
      for (int j = 0; j < 4; j++) {
        const int row = wid * 32 + fm * 16 + lh * 4 + j;
        if (m0 + row < count) {
          if (routed) {
            const int rec = recs[e * CAP + m0 + row];   // == t*8+k, the y_slot row
            const float w = tk_w[rec];
            const size_t base = (size_t)rec * H_DIM + bx * BN;
#pragma unroll
            for (int fn = 0; fn < 8; fn++)
              ((float*)OutR)[base + fn * 16 + lr] = acc[fm][fn][j] * w;
          } else {
#pragma unroll
            for (int fn = 0; fn < 8; fn++)
              ((float*)OutS)[(size_t)(m0 + row) * H_DIM + bx * BN + fn * 16 + lr] = acc[fm][fn][j];
          }
        }
      }
  }
}

// ---------------- combine: out = shared + SCALE * sum_k y_slot[t,k] ----------------
__global__ void combine_kernel(const float* __restrict__ y_slot, float* __restrict__ out) {
  const int gid = blockIdx.x * blockDim.x + threadIdx.x;
  const int t = gid >> 8;
  const int c0 = (gid & 255) * 4;
  float4 s = {0.f, 0.f, 0.f, 0.f};
#pragma unroll
  for (int k = 0; k < K_TOP; k++) {
    const float4 v = *reinterpret_cast<const float4*>(&y_slot[((size_t)t * K_TOP + k) * H_DIM + c0]);
    s.x += v.x; s.y += v.y; s.z += v.z; s.w += v.w;
  }
  float4 o = *reinterpret_cast<float4*>(&out[(size_t)t * H_DIM + c0]);
  o.x += RSCALE * s.x; o.y += RSCALE * s.y; o.z += RSCALE * s.z; o.w += RSCALE * s.w;
  *reinterpret_cast<float4*>(&out[(size_t)t * H_DIM + c0]) = o;
}

// ---------------- launch ----------------
extern "C" void kernel_launch(void* const* d_in, const int* in_sizes, int n_in,
                              void* d_out, int out_size, void* d_ws, size_t ws_size,
                              hipStream_t stream) {
  const float* x    = (const float*)d_in[0];
  const float* gw   = (const float*)d_in[1];
  const float* bias = (const float*)d_in[2];
  const float* wgu  = (const float*)d_in[3];
  const float* wd   = (const float*)d_in[4];
  const float* sgu  = (const float*)d_in[5];
  const float* sd   = (const float*)d_in[6];

  char* ws = (char*)d_ws;
  size_t o = 0;
  auto alloc = [&](size_t bytes) {
    char* p = ws + o;
    o += (bytes + 255) & ~(size_t)255;
    return (void*)p;
  };
  __bf16* xb     = (__bf16*)alloc((size_t)T_TOK * H_DIM * 2);
  __bf16* wgub   = (__bf16*)alloc((size_t)E_EXP * 2 * F_DIM * H_DIM * 2);
  __bf16* wdb    = (__bf16*)alloc((size_t)E_EXP * H_DIM * F_DIM * 2);
  __bf16* sgub   = (__bf16*)alloc((size_t)2 * FS_DIM * H_DIM * 2);
  __bf16* sdb    = (__bf16*)alloc((size_t)H_DIM * FS_DIM * 2);
  __bf16* h_buf  = (__bf16*)alloc((size_t)T_TOK * K_TOP * F_DIM * 2);
  float*  y_slot = (float*) alloc((size_t)T_TOK * K_TOP * H_DIM * 4);
  __bf16* hs     = (__bf16*)alloc((size_t)T_TOK * FS_DIM * 2);
  float* tk_w    = (float*)alloc((size_t)T_TOK * K_TOP * 4);
  int*   counts  = (int*)  alloc((size_t)E_EXP * 4);
  int*   recs    = (int*)  alloc((size_t)E_EXP * CAP * 4);
  if (o > ws_size) return;

  // 1. weight conversions (one fused dispatch)
  cvt_all<<<2048, 256, 0, stream>>>(
      wgu, wgub, E_EXP * 2 * F_DIM * H_DIM / 4,
      wd,  wdb,  E_EXP * H_DIM * F_DIM / 4,
      sgu, sgub, 2 * FS_DIM * H_DIM / 4,
      sd,  sdb,  H_DIM * FS_DIM / 4);

  // 2. routing + scatter + x conversion (counts zeroed first)
  hipMemsetAsync(counts, 0, E_EXP * 4, stream);
  route_kernel<<<T_TOK, 64, 0, stream>>>(x, gw, bias, tk_w, counts, recs, xb);

  // 3. gate_up (routed experts z<32, shared slices z=32,33)
  gemm_fused<0><<<dim3(F_DIM / 64, T_TOK / BM, E_EXP + 2), 256, 0, stream>>>(
      xb, xb, wgub, sgub, h_buf, hs, recs, counts, tk_w);

  // 4. down (routed z<32, shared z=32)
  gemm_fused<1><<<dim3(H_DIM / BN, T_TOK / BM, E_EXP + 1), 256, 0, stream>>>(
      h_buf, hs, wdb, sdb, y_slot, d_out, recs, counts, tk_w);

  // 5. combine
  combine_kernel<<<T_TOK * H_DIM / 4 / 256, 256, 0, stream>>>(y_slot, (float*)d_out);
}

// Round 6
// 310.866 us; speedup vs baseline: 1.7918x; 1.1708x over previous
//
#include <hip/hip_runtime.h>
#include <hip/hip_bf16.h>

#define T_TOK 2048
#define H_DIM 1024
#define E_EXP 32
#define F_DIM 512
#define FS_DIM 1024
#define K_TOP 8
#define NGRP 8
#define TGRP 4
#define GSZ (E_EXP / NGRP)
#define RSCALE 2.5f
#define CAP 2048

typedef short  short8 __attribute__((ext_vector_type(8)));
typedef __bf16 bf16x4 __attribute__((ext_vector_type(4)));
typedef float  f32x4  __attribute__((ext_vector_type(4)));

// ---------------- fused fp32 -> bf16 conversion for all 4 weight tensors ----------------
__global__ void cvt_all(const float* __restrict__ s0, __bf16* __restrict__ d0, int n0,
                        const float* __restrict__ s1, __bf16* __restrict__ d1, int n1,
                        const float* __restrict__ s2, __bf16* __restrict__ d2, int n2,
                        const float* __restrict__ s3, __bf16* __restrict__ d3, int n3) {
  const int ntot = n0 + n1 + n2 + n3;
  int gid = blockIdx.x * blockDim.x + threadIdx.x;
  const int stride = gridDim.x * blockDim.x;
  for (; gid < ntot; gid += stride) {
    int i = gid;
    const float* src; __bf16* dst;
    if (i < n0) { src = s0; dst = d0; }
    else { i -= n0;
      if (i < n1) { src = s1; dst = d1; }
      else { i -= n1;
        if (i < n2) { src = s2; dst = d2; }
        else { i -= n2; src = s3; dst = d3; }
      }
    }
    const float4 v = reinterpret_cast<const float4*>(src)[i];
    bf16x4 o;
    o[0] = (__bf16)v.x; o[1] = (__bf16)v.y; o[2] = (__bf16)v.z; o[3] = (__bf16)v.w;
    reinterpret_cast<bf16x4*>(dst)[i] = o;
  }
}

// ---------------- routing + x->bf16 (fp32 selection, exact reference semantics) ----------------
// NO atomics here: 8 dependent atomicAdd-with-return per wave x 2048 waves serialized
// at the device-scope path and cost 165 us in round 5. Scatter is a separate
// wave-parallel kernel (HW combines same-address lanes within one instruction).
__global__ __launch_bounds__(64) void route_kernel(
    const float* __restrict__ x, const float* __restrict__ gw,
    const float* __restrict__ bias, int* __restrict__ tk_idx,
    float* __restrict__ tk_w, __bf16* __restrict__ xb) {
  const int t = blockIdx.x;
  const int lane = threadIdx.x;
  float xr[16];
#pragma unroll
  for (int i = 0; i < 16; i++) xr[i] = x[t * H_DIM + i * 64 + lane];
  // fold x->bf16 conversion in here (row already resident)
#pragma unroll
  for (int i = 0; i < 16; i++) xb[t * H_DIM + i * 64 + lane] = (__bf16)xr[i];
  float sc[E_EXP];
#pragma unroll
  for (int e = 0; e < E_EXP; e++) {
    const float* w = gw + e * H_DIM;
    float s = 0.f;
#pragma unroll
    for (int i = 0; i < 16; i++) s += xr[i] * w[i * 64 + lane];
#pragma unroll
    for (int off = 32; off > 0; off >>= 1) s += __shfl_xor(s, off);
    sc[e] = 1.f / (1.f + expf(-s));
  }
  if (lane == 0) {
    float b[E_EXP];
    for (int e = 0; e < E_EXP; e++) b[e] = sc[e] + bias[e];
    float gs[NGRP];
    for (int g = 0; g < NGRP; g++) {
      float m1 = -1e30f, m2 = -1e30f;
      for (int j = 0; j < GSZ; j++) {
        float v = b[g * GSZ + j];
        if (v > m1) { m2 = m1; m1 = v; } else if (v > m2) { m2 = v; }
      }
      gs[g] = m1 + m2;
    }
    unsigned gmask = 0;
    for (int it = 0; it < TGRP; it++) {
      float best = -1e30f; int bi = 0;
      for (int g = 0; g < NGRP; g++)
        if (!((gmask >> g) & 1) && gs[g] > best) { best = gs[g]; bi = g; }
      gmask |= 1u << bi;
    }
    unsigned emask = 0; float wsum = 0.f;
    int idx8[K_TOP];
    for (int it = 0; it < K_TOP; it++) {
      float best = -1e30f; int bi = 0;
      for (int e = 0; e < E_EXP; e++) {
        if (!((gmask >> (e / GSZ)) & 1)) continue;
        if ((emask >> e) & 1) continue;
        if (b[e] > best) { best = b[e]; bi = e; }
      }
      emask |= 1u << bi;
      idx8[it] = bi;
      wsum += sc[bi];
    }
    const float inv = 1.f / (wsum + 1e-20f);
    for (int k = 0; k < K_TOP; k++) {
      tk_idx[t * K_TOP + k] = idx8[k];
      tk_w[t * K_TOP + k] = sc[idx8[k]] * inv;
    }
  }
}

// ---------------- scatter: wave-parallel per-lane atomics (round-2 proven) ----------------
__global__ void scatter_kernel(const int* __restrict__ tk_idx, int* __restrict__ counts,
                               int* __restrict__ recs) {
  const int i = blockIdx.x * blockDim.x + threadIdx.x;
  if (i >= T_TOK * K_TOP) return;
  const int e = tk_idx[i];
  const int pos = atomicAdd(&counts[e], 1);
  recs[e * CAP + pos] = i;  // i == t*8 + k
}

// ---------------- fused grouped+shared GEMM (m97 structure, 128x128, BK=64) ----------------
#define BM 128
#define BN 128
#define BK 64

__device__ __forceinline__ void gload_lds16(const void* g, void* l) {
  __builtin_amdgcn_global_load_lds(
      (__attribute__((address_space(1))) const void*)g,
      (__attribute__((address_space(3))) void*)l, 16, 0, 0);
}

// PHASE 0: z<32 -> GU expert z (A=xb gather, B=wgub, out=h_buf bf16 silu*up)
//          z in {32,33} -> shared GU slice s=z-32 (A=xb dense, B=sgub, out=hs)
// PHASE 1: z<32 -> DOWN expert z (A=h_buf slab, B=wdb, out=y_slot fp32 * tk_w)
//          z==32 -> shared DOWN (A=hs dense, B=sdb, out=d_out fp32)
template <int PHASE>
__global__ __launch_bounds__(256) void gemm_fused(
    const __bf16* __restrict__ Ar, const __bf16* __restrict__ As_,
    const __bf16* __restrict__ Br, const __bf16* __restrict__ Bs_,
    void* __restrict__ OutR, void* __restrict__ OutS,
    const int* __restrict__ recs, const int* __restrict__ counts,
    const float* __restrict__ tk_w) {

  const int z = blockIdx.z;
  const bool routed = (z < E_EXP);
  const int e = z;
  const int m0 = blockIdx.y * BM;
  const int bx = blockIdx.x;

  int count = T_TOK, off_e = 0;
  if (routed) {
    count = counts[e];
    for (int i = 0; i < E_EXP; i++) off_e += (i < e) ? counts[i] : 0;
    if (m0 >= count) return;
  }
  const int K = (PHASE == 0) ? H_DIM : (routed ? F_DIM : FS_DIM);

  const int tid = threadIdx.x, wid = tid >> 6, lane = tid & 63;

  __shared__ __align__(16) __bf16 Atile[BM * BK];
  __shared__ __align__(16) __bf16 Btile[BN * BK];

  const int colk = (lane & 7) * 8;
  const __bf16* aptr[4];
  const __bf16* bptr[4];
#pragma unroll
  for (int i = 0; i < 4; i++) {
    const int row = wid * 32 + i * 8 + (lane >> 3);
    int r = m0 + row; if (r > count - 1) r = count - 1;
    // ---- A source ----
    if (PHASE == 0) {
      if (routed) {
        const int rec = recs[e * CAP + r];
        aptr[i] = Ar + (size_t)(rec >> 3) * H_DIM + colk;     // gather token row of xb
      } else {
        aptr[i] = As_ + (size_t)r * H_DIM + colk;             // dense xb
      }
    } else {
      if (routed) aptr[i] = Ar + (size_t)(off_e + r) * F_DIM + colk;   // h slab
      else        aptr[i] = As_ + (size_t)r * FS_DIM + colk;           // hs dense
    }
    // ---- B source ----
    if (PHASE == 0) {
      if (routed) {
        const int brow = (row < 64) ? (bx * 64 + row) : (F_DIM + bx * 64 + row - 64);
        bptr[i] = Br + (size_t)e * 2 * F_DIM * H_DIM + (size_t)brow * H_DIM + colk;
      } else {
        const int s = z - E_EXP;
        const int fglob = s * 512 + bx * 64 + (row & 63);
        const int brow = (row < 64) ? fglob : (FS_DIM + fglob);
        bptr[i] = Bs_ + (size_t)brow * H_DIM + colk;
      }
    } else {
      if (routed) {
        const int brow = bx * BN + row;
        bptr[i] = Br + (size_t)e * H_DIM * F_DIM + (size_t)brow * F_DIM + colk;
      } else {
        const int brow = bx * BN + row;
        bptr[i] = Bs_ + (size_t)brow * FS_DIM + colk;
      }
    }
  }

  f32x4 acc[2][8];
#pragma unroll
  for (int a = 0; a < 2; a++)
#pragma unroll
    for (int b = 0; b < 8; b++) acc[a][b] = f32x4{0.f, 0.f, 0.f, 0.f};

  const int lr = lane & 15, lh = lane >> 4;

  for (int k0 = 0; k0 < K; k0 += BK) {
#pragma unroll
    for (int i = 0; i < 4; i++)
      gload_lds16(aptr[i] + k0, (char*)Atile + (wid * 4 + i) * 1024);
#pragma unroll
    for (int i = 0; i < 4; i++)
      gload_lds16(bptr[i] + k0, (char*)Btile + (wid * 4 + i) * 1024);
    __syncthreads();
#pragma unroll
    for (int kk = 0; kk < 2; kk++) {
      short8 af[2], bfr[8];
#pragma unroll
      for (int fm = 0; fm < 2; fm++)
        af[fm] = *reinterpret_cast<const short8*>(&Atile[(wid * 32 + fm * 16 + lr) * BK + kk * 32 + lh * 8]);
#pragma unroll
      for (int fn = 0; fn < 8; fn++)
        bfr[fn] = *reinterpret_cast<const short8*>(&Btile[(fn * 16 + lr) * BK + kk * 32 + lh * 8]);
#pragma unroll
      for (int fn = 0; fn < 8; fn++)
#pragma unroll
        for (int fm = 0; fm < 2; fm++)
          acc[fm][fn] = __builtin_amdgcn_mfma_f32_16x16x32_bf16(af[fm], bfr[fn], acc[fm][fn], 0, 0, 0);
    }
    __syncthreads();
  }

  // ---------------- epilogues ----------------
  if (PHASE == 0) {
    // silu(gate) * up -> bf16
#pragma unroll
    for (int fm = 0; fm < 2; fm++)
#pragma unroll
      for (int j = 0; j < 4; j++) {
        const int row = wid * 32 + fm * 16 + lh * 4 + j;
        if (m0 + row < count) {
#pragma unroll
          for (int fn = 0; fn < 4; fn++) {
            const float g = acc[fm][fn][j], u = acc[fm][fn + 4][j];
            const float hv = g / (1.f + expf(-g)) * u;
            if (routed) {
              const int f = bx * 64 + fn * 16 + lr;
              ((__bf16*)OutR)[(size_t)(off_e + m0 + row) * F_DIM + f] = (__bf16)hv;
            } else {
              const int s = z - E_EXP;
              const int f = s * 512 + bx * 64 + fn * 16 + lr;
              ((__bf16*)OutS)[(size_t)(m0 + row) * FS_DIM + f] = (__bf16)hv;
            }
          }
        }
      }
  } else {
#pragma unroll
    for (int fm = 0; fm < 2; fm++)
#pragma unroll
      for (int j = 0; j < 4; j++) {
        const int row = wid * 32 + fm * 16 + lh * 4 + j;
        if (m0 + row < count) {
          if (routed) {
            const int rec = recs[e * CAP + m0 + row];   // == t*8+k, the y_slot row
            const float w = tk_w[rec];
            const size_t base = (size_t)rec * H_DIM + bx * BN;
#pragma unroll
            for (int fn = 0; fn < 8; fn++)
              ((float*)OutR)[base + fn * 16 + lr] = acc[fm][fn][j] * w;
          } else {
#pragma unroll
            for (int fn = 0; fn < 8; fn++)
              ((float*)OutS)[(size_t)(m0 + row) * H_DIM + bx * BN + fn * 16 + lr] = acc[fm][fn][j];
          }
        }
      }
  }
}

// ---------------- combine: out = shared + SCALE * sum_k y_slot[t,k] ----------------
__global__ void combine_kernel(const float* __restrict__ y_slot, float* __restrict__ out) {
  const int gid = blockIdx.x * blockDim.x + threadIdx.x;
  const int t = gid >> 8;
  const int c0 = (gid & 255) * 4;
  float4 s = {0.f, 0.f, 0.f, 0.f};
#pragma unroll
  for (int k = 0; k < K_TOP; k++) {
    const float4 v = *reinterpret_cast<const float4*>(&y_slot[((size_t)t * K_TOP + k) * H_DIM + c0]);
    s.x += v.x; s.y += v.y; s.z += v.z; s.w += v.w;
  }
  float4 o = *reinterpret_cast<float4*>(&out[(size_t)t * H_DIM + c0]);
  o.x += RSCALE * s.x; o.y += RSCALE * s.y; o.z += RSCALE * s.z; o.w += RSCALE * s.w;
  *reinterpret_cast<float4*>(&out[(size_t)t * H_DIM + c0]) = o;
}

// ---------------- launch ----------------
extern "C" void kernel_launch(void* const* d_in, const int* in_sizes, int n_in,
                              void* d_out, int out_size, void* d_ws, size_t ws_size,
                              hipStream_t stream) {
  const float* x    = (const float*)d_in[0];
  const float* gw   = (const float*)d_in[1];
  const float* bias = (const float*)d_in[2];
  const float* wgu  = (const float*)d_in[3];
  const float* wd   = (const float*)d_in[4];
  const float* sgu  = (const float*)d_in[5];
  const float* sd   = (const float*)d_in[6];

  char* ws = (char*)d_ws;
  size_t o = 0;
  auto alloc = [&](size_t bytes) {
    char* p = ws + o;
    o += (bytes + 255) & ~(size_t)255;
    return (void*)p;
  };
  __bf16* xb     = (__bf16*)alloc((size_t)T_TOK * H_DIM * 2);
  __bf16* wgub   = (__bf16*)alloc((size_t)E_EXP * 2 * F_DIM * H_DIM * 2);
  __bf16* wdb    = (__bf16*)alloc((size_t)E_EXP * H_DIM * F_DIM * 2);
  __bf16* sgub   = (__bf16*)alloc((size_t)2 * FS_DIM * H_DIM * 2);
  __bf16* sdb    = (__bf16*)alloc((size_t)H_DIM * FS_DIM * 2);
  __bf16* h_buf  = (__bf16*)alloc((size_t)T_TOK * K_TOP * F_DIM * 2);
  float*  y_slot = (float*) alloc((size_t)T_TOK * K_TOP * H_DIM * 4);
  __bf16* hs     = (__bf16*)alloc((size_t)T_TOK * FS_DIM * 2);
  int*   tk_idx  = (int*)  alloc((size_t)T_TOK * K_TOP * 4);
  float* tk_w    = (float*)alloc((size_t)T_TOK * K_TOP * 4);
  int*   counts  = (int*)  alloc((size_t)E_EXP * 4);
  int*   recs    = (int*)  alloc((size_t)E_EXP * CAP * 4);
  if (o > ws_size) return;

  // 1. weight conversions (one fused dispatch)
  cvt_all<<<2048, 256, 0, stream>>>(
      wgu, wgub, E_EXP * 2 * F_DIM * H_DIM / 4,
      wd,  wdb,  E_EXP * H_DIM * F_DIM / 4,
      sgu, sgub, 2 * FS_DIM * H_DIM / 4,
      sd,  sdb,  H_DIM * FS_DIM / 4);

  // 2. routing + x conversion (no atomics)
  route_kernel<<<T_TOK, 64, 0, stream>>>(x, gw, bias, tk_idx, tk_w, xb);

  // 3. scatter (wave-parallel atomics)
  hipMemsetAsync(counts, 0, E_EXP * 4, stream);
  scatter_kernel<<<(T_TOK * K_TOP + 255) / 256, 256, 0, stream>>>(tk_idx, counts, recs);

  // 4. gate_up (routed experts z<32, shared slices z=32,33)
  gemm_fused<0><<<dim3(F_DIM / 64, T_TOK / BM, E_EXP + 2), 256, 0, stream>>>(
      xb, xb, wgub, sgub, h_buf, hs, recs, counts, tk_w);

  // 5. down (routed z<32, shared z=32)
  gemm_fused<1><<<dim3(H_DIM / BN, T_TOK / BM, E_EXP + 1), 256, 0, stream>>>(
      h_buf, hs, wdb, sdb, y_slot, d_out, recs, counts, tk_w);

  // 6. combine
  combine_kernel<<<T_TOK * H_DIM / 4 / 256, 256, 0, stream>>>(y_slot, (float*)d_out);
}